// Round 10
// baseline (282.595 us; speedup 1.0000x reference)
//
#include <hip/hip_runtime.h>

// ---------------------------------------------------------------------------
// HabitatGNN: 2-layer GCN (self loops, symmetric norm) + linear head.
// x:[N,128] f32, edge_index:[2,E] int32, W1:[128,64], W2:[64,32], Wc:[32,1].
//
// R5: atomic scatter = 75% of runtime -> CSR + gather.
// R6: single-block scan = 51% of total -> 3-phase device-wide scan.
// R7: gemm 70us, occupancy 14% -> quad-per-node (4 lanes/node). 70->44us.
// R8: 512-block occupancy lever: NEUTRAL (44us, occ 27->34) -> wrong model.
// R9: gemm is LDS-BW-bound: 4B LDS read per MAC = 3.28GB @69TB/s = 47us ~=
//     measured 44. -> R=4 node register-blocking: one W float4 read feeds 4
//     nodes (1B/MAC, 0.82GB -> ~12us floor). 128-thread blocks keep 256 CUs
//     fed (782 blocks, ~3/CU).
// ---------------------------------------------------------------------------

#define SCAN_THREADS 256
#define SCAN_PER_T   8
#define SCAN_TILE    (SCAN_THREADS * SCAN_PER_T)   // 2048 elements per block

__global__ __launch_bounds__(256) void count_kernel(const int* __restrict__ dst,
                                                    int* __restrict__ deg, int E) {
    int e = blockIdx.x * blockDim.x + threadIdx.x;
    if (e < E) atomicAdd(&deg[dst[e]], 1);
}

// Phase A: per-block tile sum.
__global__ __launch_bounds__(SCAN_THREADS) void tile_reduce_kernel(const int* __restrict__ deg,
                                                                   int* __restrict__ bsum,
                                                                   int n) {
    __shared__ int s[SCAN_THREADS];
    int t = threadIdx.x;
    int gbase = blockIdx.x * SCAN_TILE + t * SCAN_PER_T;
    int local = 0;
#pragma unroll
    for (int k = 0; k < SCAN_PER_T; ++k) {
        int i = gbase + k;
        if (i < n) local += deg[i];
    }
    s[t] = local;
    __syncthreads();
    for (int off = SCAN_THREADS / 2; off > 0; off >>= 1) {
        if (t < off) s[t] += s[t + off];
        __syncthreads();
    }
    if (t == 0) bsum[blockIdx.x] = s[0];
}

// Phase B: scan the <=256 block sums (exclusive, in place); row_ptr[n] = total.
__global__ __launch_bounds__(SCAN_THREADS) void scan_bsums_kernel(int* __restrict__ bsum,
                                                                  int* __restrict__ row_ptr,
                                                                  int nb, int n) {
    __shared__ int s[SCAN_THREADS];
    int t = threadIdx.x;
    s[t] = (t < nb) ? bsum[t] : 0;
    __syncthreads();
    for (int off = 1; off < SCAN_THREADS; off <<= 1) {
        int v = (t >= off) ? s[t - off] : 0;
        __syncthreads();
        s[t] += v;
        __syncthreads();
    }
    if (t < nb) bsum[t] = (t == 0) ? 0 : s[t - 1];   // exclusive prefix
    if (t == 0) row_ptr[n] = s[nb - 1];              // == E
}

// Phase C: re-scan tile, add block prefix; write row_ptr, cursor, dinv.
__global__ __launch_bounds__(SCAN_THREADS) void tile_apply_kernel(int* __restrict__ deg,
                                                                  const int* __restrict__ bsum,
                                                                  int* __restrict__ row_ptr,
                                                                  float* __restrict__ dinv,
                                                                  int n) {
    __shared__ int s[SCAN_THREADS];
    int t = threadIdx.x;
    int gbase = blockIdx.x * SCAN_TILE + t * SCAN_PER_T;

    int d[SCAN_PER_T];
    int inc[SCAN_PER_T];
    int run = 0;
#pragma unroll
    for (int k = 0; k < SCAN_PER_T; ++k) {
        int i = gbase + k;
        d[k] = (i < n) ? deg[i] : 0;
        run += d[k];
        inc[k] = run;                      // inclusive within thread
    }
    s[t] = run;
    __syncthreads();
    for (int off = 1; off < SCAN_THREADS; off <<= 1) {
        int v = (t >= off) ? s[t - off] : 0;
        __syncthreads();
        s[t] += v;
        __syncthreads();
    }
    int base = bsum[blockIdx.x] + ((t == 0) ? 0 : s[t - 1]);
#pragma unroll
    for (int k = 0; k < SCAN_PER_T; ++k) {
        int i = gbase + k;
        if (i < n) {
            int ex = base + inc[k] - d[k];          // exclusive prefix for i
            row_ptr[i] = ex;
            deg[i] = ex;                            // fill cursor
            dinv[i] = rsqrtf((float)(d[k] + 1));    // +1 = self loop
        }
    }
}

__global__ __launch_bounds__(256) void fill_kernel(const int* __restrict__ src,
                                                   const int* __restrict__ dst,
                                                   int* __restrict__ cursor,
                                                   int* __restrict__ col, int E) {
    int e = blockIdx.x * blockDim.x + threadIdx.x;
    if (e < E) {
        int pos = atomicAdd(&cursor[dst[e]], 1);
        col[pos] = src[e];
    }
}

// H[n, OUT] = X[n, IN] @ W[IN, OUT]. Quad-per-R-nodes: 4 adjacent lanes share
// R=4 nodes; each lane owns an OUT/4 output strip for all 4 nodes. Each W
// float4 LDS read feeds R nodes -> 1B LDS per MAC (was 4B: LDS-BW-bound).
template <int IN, int OUT, int R>
__global__ __launch_bounds__(128) void gemm_kernel(const float* __restrict__ X,
                                                   const float* __restrict__ W,
                                                   float* __restrict__ H, int n) {
    constexpr int STRIP = OUT / 4;         // 16 (layer1) / 8 (layer2)
    __shared__ float Ws[IN * OUT];
    for (int i = threadIdx.x; i < IN * OUT / 4; i += blockDim.x)
        ((float4*)Ws)[i] = ((const float4*)W)[i];
    __syncthreads();

    int t = blockIdx.x * blockDim.x + threadIdx.x;
    int quad = t >> 2;
    int strip = (t & 3) * STRIP;
    int node0 = quad * R;
    if (node0 >= n) return;

    float acc[R][STRIP];
#pragma unroll
    for (int r = 0; r < R; ++r)
#pragma unroll
        for (int j = 0; j < STRIP; ++j) acc[r][j] = 0.f;

    // row pointers, clamped so OOB lanes just duplicate the last row (stores
    // are guarded; n=100000 is divisible by R=4 so clamp never fires here)
    const float* xr[R];
#pragma unroll
    for (int r = 0; r < R; ++r) {
        int nr = node0 + r;
        if (nr > n - 1) nr = n - 1;
        xr[r] = X + (size_t)nr * IN;
    }

#pragma unroll 2
    for (int k = 0; k < IN; k += 4) {
        float4 xv[R];
#pragma unroll
        for (int r = 0; r < R; ++r)
            xv[r] = *(const float4*)(xr[r] + k);   // quad-broadcast addresses
#pragma unroll
        for (int jg = 0; jg < STRIP; jg += 4) {
            float4 a  = *(const float4*)(Ws + (k + 0) * OUT + strip + jg);
            float4 b  = *(const float4*)(Ws + (k + 1) * OUT + strip + jg);
            float4 c  = *(const float4*)(Ws + (k + 2) * OUT + strip + jg);
            float4 dd = *(const float4*)(Ws + (k + 3) * OUT + strip + jg);
#pragma unroll
            for (int r = 0; r < R; ++r) {
                acc[r][jg + 0] += xv[r].x * a.x + xv[r].y * b.x + xv[r].z * c.x + xv[r].w * dd.x;
                acc[r][jg + 1] += xv[r].x * a.y + xv[r].y * b.y + xv[r].z * c.y + xv[r].w * dd.y;
                acc[r][jg + 2] += xv[r].x * a.z + xv[r].y * b.z + xv[r].z * c.z + xv[r].w * dd.z;
                acc[r][jg + 3] += xv[r].x * a.w + xv[r].y * b.w + xv[r].z * c.w + xv[r].w * dd.w;
            }
        }
    }

#pragma unroll
    for (int r = 0; r < R; ++r) {
        int nr = node0 + r;
        if (nr < n) {
            float* hr = H + (size_t)nr * OUT + strip;
#pragma unroll
            for (int j = 0; j < STRIP; j += 4)
                *(float4*)(hr + j) =
                    make_float4(acc[r][j], acc[r][j + 1], acc[r][j + 2], acc[r][j + 3]);
        }
    }
}

// Gather aggregation, F/4 threads per node, each owns a float4 column.
// OUT[i] = relu(dinv[i]*Sum dinv[s]*H[s] + dinv[i]^2*H[i] + b)
// 2-way edge unroll: doubles outstanding gather loads.
template <int F>
__global__ __launch_bounds__(256) void agg_relu_kernel(const int* __restrict__ row_ptr,
                                                       const int* __restrict__ col,
                                                       const float* __restrict__ dinv,
                                                       const float* __restrict__ H,
                                                       const float* __restrict__ b,
                                                       float* __restrict__ OUT, int n) {
    constexpr int TPE = F / 4;
    int t = blockIdx.x * blockDim.x + threadIdx.x;
    int node = t / TPE;
    int c = t % TPE;
    if (node >= n) return;
    int rs = row_ptr[node], re = row_ptr[node + 1];
    float di = dinv[node];
    float4 acc = make_float4(0.f, 0.f, 0.f, 0.f);
    int e = rs;
    for (; e + 1 < re; e += 2) {
        int s0 = col[e], s1 = col[e + 1];
        float w0 = dinv[s0], w1 = dinv[s1];
        float4 v0 = *(const float4*)(H + (size_t)s0 * F + c * 4);
        float4 v1 = *(const float4*)(H + (size_t)s1 * F + c * 4);
        acc.x += w0 * v0.x + w1 * v1.x;
        acc.y += w0 * v0.y + w1 * v1.y;
        acc.z += w0 * v0.z + w1 * v1.z;
        acc.w += w0 * v0.w + w1 * v1.w;
    }
    if (e < re) {
        int s0 = col[e];
        float w0 = dinv[s0];
        float4 v0 = *(const float4*)(H + (size_t)s0 * F + c * 4);
        acc.x += w0 * v0.x; acc.y += w0 * v0.y;
        acc.z += w0 * v0.z; acc.w += w0 * v0.w;
    }
    float4 hs = *(const float4*)(H + (size_t)node * F + c * 4);
    float4 bb = *(const float4*)(b + c * 4);
    float d2 = di * di;
    float4 r;
    r.x = di * acc.x + d2 * hs.x + bb.x;
    r.y = di * acc.y + d2 * hs.y + bb.y;
    r.z = di * acc.z + d2 * hs.z + bb.z;
    r.w = di * acc.w + d2 * hs.w + bb.w;
    r.x = r.x > 0.f ? r.x : 0.f;
    r.y = r.y > 0.f ? r.y : 0.f;
    r.z = r.z > 0.f ? r.z : 0.f;
    r.w = r.w > 0.f ? r.w : 0.f;
    *(float4*)(OUT + (size_t)node * F + c * 4) = r;
}

// Layer-2 aggregation fused with the classifier head:
// out[i] = relu(agg(H2)[i] + b2) . Wc + bc  (8 lanes per node, shfl reduce)
__global__ __launch_bounds__(256) void agg_final_kernel(const int* __restrict__ row_ptr,
                                                        const int* __restrict__ col,
                                                        const float* __restrict__ dinv,
                                                        const float* __restrict__ H,
                                                        const float* __restrict__ b2,
                                                        const float* __restrict__ Wc,
                                                        const float* __restrict__ bc,
                                                        float* __restrict__ out, int n) {
    constexpr int F = 32, TPE = 8;
    int t = blockIdx.x * blockDim.x + threadIdx.x;
    int node = t / TPE;
    int c = t % TPE;
    if (node >= n) return;
    int rs = row_ptr[node], re = row_ptr[node + 1];
    float di = dinv[node];
    float4 acc = make_float4(0.f, 0.f, 0.f, 0.f);
    int e = rs;
    for (; e + 1 < re; e += 2) {
        int s0 = col[e], s1 = col[e + 1];
        float w0 = dinv[s0], w1 = dinv[s1];
        float4 v0 = *(const float4*)(H + (size_t)s0 * F + c * 4);
        float4 v1 = *(const float4*)(H + (size_t)s1 * F + c * 4);
        acc.x += w0 * v0.x + w1 * v1.x;
        acc.y += w0 * v0.y + w1 * v1.y;
        acc.z += w0 * v0.z + w1 * v1.z;
        acc.w += w0 * v0.w + w1 * v1.w;
    }
    if (e < re) {
        int s0 = col[e];
        float w0 = dinv[s0];
        float4 v0 = *(const float4*)(H + (size_t)s0 * F + c * 4);
        acc.x += w0 * v0.x; acc.y += w0 * v0.y;
        acc.z += w0 * v0.z; acc.w += w0 * v0.w;
    }
    float4 hs = *(const float4*)(H + (size_t)node * F + c * 4);
    float4 bb = *(const float4*)(b2 + c * 4);
    float4 wc = *(const float4*)(Wc + c * 4);
    float d2 = di * di;
    float4 r;
    r.x = di * acc.x + d2 * hs.x + bb.x;
    r.y = di * acc.y + d2 * hs.y + bb.y;
    r.z = di * acc.z + d2 * hs.z + bb.z;
    r.w = di * acc.w + d2 * hs.w + bb.w;
    float dot = (r.x > 0.f ? r.x : 0.f) * wc.x + (r.y > 0.f ? r.y : 0.f) * wc.y +
                (r.z > 0.f ? r.z : 0.f) * wc.z + (r.w > 0.f ? r.w : 0.f) * wc.w;
    dot += __shfl_xor(dot, 1, 8);
    dot += __shfl_xor(dot, 2, 8);
    dot += __shfl_xor(dot, 4, 8);
    if (c == 0) out[node] = dot + bc[0];
}

extern "C" void kernel_launch(void* const* d_in, const int* in_sizes, int n_in,
                              void* d_out, int out_size, void* d_ws, size_t ws_size,
                              hipStream_t stream) {
    const float* x  = (const float*)d_in[0];
    const int*   ei = (const int*)d_in[1];  // int32 edge_index
    const float* W1 = (const float*)d_in[2];
    const float* b1 = (const float*)d_in[3];
    const float* W2 = (const float*)d_in[4];
    const float* b2 = (const float*)d_in[5];
    const float* Wc = (const float*)d_in[6];
    const float* bc = (const float*)d_in[7];
    float* out = (float*)d_out;

    const int n = in_sizes[0] / 128;   // 100000
    const int E = in_sizes[1] / 2;     // 600000

    const int* src = ei;
    const int* dst = ei + (size_t)E;

    const int nb = (n + SCAN_TILE - 1) / SCAN_TILE;   // 49 blocks (must be <=256)

    // ws layout (4B elems): dinv[n] | deg/cursor[n] | row_ptr[n+1] | col[E]
    //                       | bsum[256] | bufA[64n] | bufB[64n]    (~54.8 MB)
    float* dinv    = (float*)d_ws;
    int*   deg     = (int*)d_ws + n;
    int*   row_ptr = (int*)d_ws + 2 * (size_t)n;
    int*   col     = row_ptr + (n + 1);
    int*   bsum    = col + E;
    float* bufA    = (float*)(bsum + 256);     // h1, then h2
    float* bufB    = bufA + (size_t)n * 64;    // hr1

    hipMemsetAsync(deg, 0, (size_t)n * 4, stream);
    count_kernel<<<(E + 255) / 256, 256, 0, stream>>>(dst, deg, E);
    tile_reduce_kernel<<<nb, SCAN_THREADS, 0, stream>>>(deg, bsum, n);
    scan_bsums_kernel<<<1, SCAN_THREADS, 0, stream>>>(bsum, row_ptr, nb, n);
    tile_apply_kernel<<<nb, SCAN_THREADS, 0, stream>>>(deg, bsum, row_ptr, dinv, n);
    fill_kernel<<<(E + 255) / 256, 256, 0, stream>>>(src, dst, deg, col, E);

    // Layer 1  (R=4 node blocking: threads = ceil(n/4)*4)
    {
        int thr = ((n + 3) / 4) * 4;
        gemm_kernel<128, 64, 4><<<(thr + 127) / 128, 128, 0, stream>>>(x, W1, bufA, n);
    }
    agg_relu_kernel<64><<<(n * 16 + 255) / 256, 256, 0, stream>>>(row_ptr, col, dinv,
                                                                  bufA, b1, bufB, n);
    // Layer 2 + head
    {
        int thr = ((n + 3) / 4) * 4;
        gemm_kernel<64, 32, 4><<<(thr + 127) / 128, 128, 0, stream>>>(bufB, W2, bufA, n);
    }
    agg_final_kernel<<<(n * 8 + 255) / 256, 256, 0, stream>>>(row_ptr, col, dinv,
                                                              bufA, b2, Wc, bc, out, n);
}

// Round 11
// 275.658 us; speedup vs baseline: 1.0252x; 1.0252x over previous
//
#include <hip/hip_runtime.h>

// ---------------------------------------------------------------------------
// HabitatGNN: 2-layer GCN (self loops, symmetric norm) + linear head.
// x:[N,128] f32, edge_index:[2,E] int32, W1:[128,64], W2:[64,32], Wc:[32,1].
//
// R5:  atomic scatter = 75% of runtime -> CSR + gather.
// R6:  single-block scan = 51% of total -> 3-phase device-wide scan.
// R7:  gemm 70us, occ 14% -> quad-per-node. 70->44us.
// R8:  512-block occupancy lever: NEUTRAL (44us) -> LDS-BW model.
// R9/10: R=4 reg-blocking cut LDS traffic but threads 400k->100k: 6 waves/CU,
//      latency-bound, 56us REGRESSION. Need high wave count AND low LDS/MAC.
// R11: X staged in LDS (stride-33 rows, conflict-free, coalesced staging);
//      W via wave-uniform global reads -> s_load/SGPR operands (scalar cache);
//      lane=node, waves split OUT in halves. 0.13B LDS/MAC, 12 waves/CU.
// ---------------------------------------------------------------------------

#define SCAN_THREADS 256
#define SCAN_PER_T   8
#define SCAN_TILE    (SCAN_THREADS * SCAN_PER_T)   // 2048 elements per block

__global__ __launch_bounds__(256) void count_kernel(const int* __restrict__ dst,
                                                    int* __restrict__ deg, int E) {
    int e = blockIdx.x * blockDim.x + threadIdx.x;
    if (e < E) atomicAdd(&deg[dst[e]], 1);
}

// Phase A: per-block tile sum.
__global__ __launch_bounds__(SCAN_THREADS) void tile_reduce_kernel(const int* __restrict__ deg,
                                                                   int* __restrict__ bsum,
                                                                   int n) {
    __shared__ int s[SCAN_THREADS];
    int t = threadIdx.x;
    int gbase = blockIdx.x * SCAN_TILE + t * SCAN_PER_T;
    int local = 0;
#pragma unroll
    for (int k = 0; k < SCAN_PER_T; ++k) {
        int i = gbase + k;
        if (i < n) local += deg[i];
    }
    s[t] = local;
    __syncthreads();
    for (int off = SCAN_THREADS / 2; off > 0; off >>= 1) {
        if (t < off) s[t] += s[t + off];
        __syncthreads();
    }
    if (t == 0) bsum[blockIdx.x] = s[0];
}

// Phase B: scan the <=256 block sums (exclusive, in place); row_ptr[n] = total.
__global__ __launch_bounds__(SCAN_THREADS) void scan_bsums_kernel(int* __restrict__ bsum,
                                                                  int* __restrict__ row_ptr,
                                                                  int nb, int n) {
    __shared__ int s[SCAN_THREADS];
    int t = threadIdx.x;
    s[t] = (t < nb) ? bsum[t] : 0;
    __syncthreads();
    for (int off = 1; off < SCAN_THREADS; off <<= 1) {
        int v = (t >= off) ? s[t - off] : 0;
        __syncthreads();
        s[t] += v;
        __syncthreads();
    }
    if (t < nb) bsum[t] = (t == 0) ? 0 : s[t - 1];   // exclusive prefix
    if (t == 0) row_ptr[n] = s[nb - 1];              // == E
}

// Phase C: re-scan tile, add block prefix; write row_ptr, cursor, dinv.
__global__ __launch_bounds__(SCAN_THREADS) void tile_apply_kernel(int* __restrict__ deg,
                                                                  const int* __restrict__ bsum,
                                                                  int* __restrict__ row_ptr,
                                                                  float* __restrict__ dinv,
                                                                  int n) {
    __shared__ int s[SCAN_THREADS];
    int t = threadIdx.x;
    int gbase = blockIdx.x * SCAN_TILE + t * SCAN_PER_T;

    int d[SCAN_PER_T];
    int inc[SCAN_PER_T];
    int run = 0;
#pragma unroll
    for (int k = 0; k < SCAN_PER_T; ++k) {
        int i = gbase + k;
        d[k] = (i < n) ? deg[i] : 0;
        run += d[k];
        inc[k] = run;                      // inclusive within thread
    }
    s[t] = run;
    __syncthreads();
    for (int off = 1; off < SCAN_THREADS; off <<= 1) {
        int v = (t >= off) ? s[t - off] : 0;
        __syncthreads();
        s[t] += v;
        __syncthreads();
    }
    int base = bsum[blockIdx.x] + ((t == 0) ? 0 : s[t - 1]);
#pragma unroll
    for (int k = 0; k < SCAN_PER_T; ++k) {
        int i = gbase + k;
        if (i < n) {
            int ex = base + inc[k] - d[k];          // exclusive prefix for i
            row_ptr[i] = ex;
            deg[i] = ex;                            // fill cursor
            dinv[i] = rsqrtf((float)(d[k] + 1));    // +1 = self loop
        }
    }
}

__global__ __launch_bounds__(256) void fill_kernel(const int* __restrict__ src,
                                                   const int* __restrict__ dst,
                                                   int* __restrict__ cursor,
                                                   int* __restrict__ col, int E) {
    int e = blockIdx.x * blockDim.x + threadIdx.x;
    if (e < E) {
        int pos = atomicAdd(&cursor[dst[e]], 1);
        col[pos] = src[e];
    }
}

// H[n, OUT] = X[n, IN] @ W[IN, OUT].
// 256 threads / 128 nodes per block; lane = node within a 64-node half;
// wave pairs split OUT in halves (jbase wave-uniform via readfirstlane so W
// reads are SGPR s_loads through the scalar cache -- W never touches LDS).
// X staged per 32-wide k-tile in LDS with stride-33 rows (gcd(33,32)=1 ->
// conflict-free lane-per-row reads; staging loads are coalesced float4).
template <int IN, int OUT>
__global__ __launch_bounds__(256) void gemm_kernel(const float* __restrict__ X,
                                                   const float* __restrict__ W,
                                                   float* __restrict__ H, int n) {
    constexpr int NB = 128;            // nodes per block
    constexpr int KT = 32;             // k-tile
    constexpr int STRIDE = KT + 1;     // 33 floats -> conflict-free rows
    constexpr int JW = OUT / 2;        // per-wave output slice (32 / 16)
    constexpr int NKT = IN / KT;       // 4 (layer1) / 2 (layer2)
    constexpr int NF4 = NB * KT / 4;   // float4s per staged tile = 1024

    __shared__ float Xs[NB * STRIDE];  // 16,896 B

    const int t = threadIdx.x;
    const int wv = __builtin_amdgcn_readfirstlane(t >> 6);  // wave id, uniform
    const int lane = t & 63;
    const int node0 = blockIdx.x * NB;
    const int lnode = ((wv >> 1) << 6) + lane;   // 0..127: which staged row
    const int jbase = (wv & 1) * JW;             // uniform per wave
    const int node = node0 + lnode;

    float acc[JW];
#pragma unroll
    for (int j = 0; j < JW; ++j) acc[j] = 0.f;

    for (int kt = 0; kt < NKT; ++kt) {
        __syncthreads();   // previous tile fully consumed
        for (int f = t; f < NF4; f += 256) {
            int nd = f >> 3;           // KT/4 = 8 float4s per node row
            int kq = f & 7;
            float4 val = make_float4(0.f, 0.f, 0.f, 0.f);
            if (node0 + nd < n)
                val = *(const float4*)(X + (size_t)(node0 + nd) * IN + kt * KT + kq * 4);
            float* p = Xs + nd * STRIDE + kq * 4;   // stride 33: write as b32s
            p[0] = val.x; p[1] = val.y; p[2] = val.z; p[3] = val.w;
        }
        __syncthreads();

        const float* xrow = Xs + lnode * STRIDE;
#pragma unroll
        for (int kq = 0; kq < KT; kq += 4) {
            float x0 = xrow[kq + 0];
            float x1 = xrow[kq + 1];
            float x2 = xrow[kq + 2];
            float x3 = xrow[kq + 3];
            const float* wr = W + (size_t)(kt * KT + kq) * OUT + jbase;  // uniform
#pragma unroll
            for (int jg = 0; jg < JW; jg += 4) {
                float4 w0 = *(const float4*)(wr + 0 * OUT + jg);
                float4 w1 = *(const float4*)(wr + 1 * OUT + jg);
                float4 w2 = *(const float4*)(wr + 2 * OUT + jg);
                float4 w3 = *(const float4*)(wr + 3 * OUT + jg);
                acc[jg + 0] += x0 * w0.x + x1 * w1.x + x2 * w2.x + x3 * w3.x;
                acc[jg + 1] += x0 * w0.y + x1 * w1.y + x2 * w2.y + x3 * w3.y;
                acc[jg + 2] += x0 * w0.z + x1 * w1.z + x2 * w2.z + x3 * w3.z;
                acc[jg + 3] += x0 * w0.w + x1 * w1.w + x2 * w2.w + x3 * w3.w;
            }
        }
    }

    if (node < n) {
        float* hr = H + (size_t)node * OUT + jbase;
#pragma unroll
        for (int jg = 0; jg < JW; jg += 4)
            *(float4*)(hr + jg) =
                make_float4(acc[jg], acc[jg + 1], acc[jg + 2], acc[jg + 3]);
    }
}

// Gather aggregation, F/4 threads per node, each owns a float4 column.
// OUT[i] = relu(dinv[i]*Sum dinv[s]*H[s] + dinv[i]^2*H[i] + b)
template <int F>
__global__ __launch_bounds__(256) void agg_relu_kernel(const int* __restrict__ row_ptr,
                                                       const int* __restrict__ col,
                                                       const float* __restrict__ dinv,
                                                       const float* __restrict__ H,
                                                       const float* __restrict__ b,
                                                       float* __restrict__ OUT, int n) {
    constexpr int TPE = F / 4;
    int t = blockIdx.x * blockDim.x + threadIdx.x;
    int node = t / TPE;
    int c = t % TPE;
    if (node >= n) return;
    int rs = row_ptr[node], re = row_ptr[node + 1];
    float di = dinv[node];
    float4 acc = make_float4(0.f, 0.f, 0.f, 0.f);
    int e = rs;
    for (; e + 1 < re; e += 2) {
        int s0 = col[e], s1 = col[e + 1];
        float w0 = dinv[s0], w1 = dinv[s1];
        float4 v0 = *(const float4*)(H + (size_t)s0 * F + c * 4);
        float4 v1 = *(const float4*)(H + (size_t)s1 * F + c * 4);
        acc.x += w0 * v0.x + w1 * v1.x;
        acc.y += w0 * v0.y + w1 * v1.y;
        acc.z += w0 * v0.z + w1 * v1.z;
        acc.w += w0 * v0.w + w1 * v1.w;
    }
    if (e < re) {
        int s0 = col[e];
        float w0 = dinv[s0];
        float4 v0 = *(const float4*)(H + (size_t)s0 * F + c * 4);
        acc.x += w0 * v0.x; acc.y += w0 * v0.y;
        acc.z += w0 * v0.z; acc.w += w0 * v0.w;
    }
    float4 hs = *(const float4*)(H + (size_t)node * F + c * 4);
    float4 bb = *(const float4*)(b + c * 4);
    float d2 = di * di;
    float4 r;
    r.x = di * acc.x + d2 * hs.x + bb.x;
    r.y = di * acc.y + d2 * hs.y + bb.y;
    r.z = di * acc.z + d2 * hs.z + bb.z;
    r.w = di * acc.w + d2 * hs.w + bb.w;
    r.x = r.x > 0.f ? r.x : 0.f;
    r.y = r.y > 0.f ? r.y : 0.f;
    r.z = r.z > 0.f ? r.z : 0.f;
    r.w = r.w > 0.f ? r.w : 0.f;
    *(float4*)(OUT + (size_t)node * F + c * 4) = r;
}

// Layer-2 aggregation fused with the classifier head:
// out[i] = relu(agg(H2)[i] + b2) . Wc + bc  (8 lanes per node, shfl reduce)
__global__ __launch_bounds__(256) void agg_final_kernel(const int* __restrict__ row_ptr,
                                                        const int* __restrict__ col,
                                                        const float* __restrict__ dinv,
                                                        const float* __restrict__ H,
                                                        const float* __restrict__ b2,
                                                        const float* __restrict__ Wc,
                                                        const float* __restrict__ bc,
                                                        float* __restrict__ out, int n) {
    constexpr int F = 32, TPE = 8;
    int t = blockIdx.x * blockDim.x + threadIdx.x;
    int node = t / TPE;
    int c = t % TPE;
    if (node >= n) return;
    int rs = row_ptr[node], re = row_ptr[node + 1];
    float di = dinv[node];
    float4 acc = make_float4(0.f, 0.f, 0.f, 0.f);
    int e = rs;
    for (; e + 1 < re; e += 2) {
        int s0 = col[e], s1 = col[e + 1];
        float w0 = dinv[s0], w1 = dinv[s1];
        float4 v0 = *(const float4*)(H + (size_t)s0 * F + c * 4);
        float4 v1 = *(const float4*)(H + (size_t)s1 * F + c * 4);
        acc.x += w0 * v0.x + w1 * v1.x;
        acc.y += w0 * v0.y + w1 * v1.y;
        acc.z += w0 * v0.z + w1 * v1.z;
        acc.w += w0 * v0.w + w1 * v1.w;
    }
    if (e < re) {
        int s0 = col[e];
        float w0 = dinv[s0];
        float4 v0 = *(const float4*)(H + (size_t)s0 * F + c * 4);
        acc.x += w0 * v0.x; acc.y += w0 * v0.y;
        acc.z += w0 * v0.z; acc.w += w0 * v0.w;
    }
    float4 hs = *(const float4*)(H + (size_t)node * F + c * 4);
    float4 bb = *(const float4*)(b2 + c * 4);
    float4 wc = *(const float4*)(Wc + c * 4);
    float d2 = di * di;
    float4 r;
    r.x = di * acc.x + d2 * hs.x + bb.x;
    r.y = di * acc.y + d2 * hs.y + bb.y;
    r.z = di * acc.z + d2 * hs.z + bb.z;
    r.w = di * acc.w + d2 * hs.w + bb.w;
    float dot = (r.x > 0.f ? r.x : 0.f) * wc.x + (r.y > 0.f ? r.y : 0.f) * wc.y +
                (r.z > 0.f ? r.z : 0.f) * wc.z + (r.w > 0.f ? r.w : 0.f) * wc.w;
    dot += __shfl_xor(dot, 1, 8);
    dot += __shfl_xor(dot, 2, 8);
    dot += __shfl_xor(dot, 4, 8);
    if (c == 0) out[node] = dot + bc[0];
}

extern "C" void kernel_launch(void* const* d_in, const int* in_sizes, int n_in,
                              void* d_out, int out_size, void* d_ws, size_t ws_size,
                              hipStream_t stream) {
    const float* x  = (const float*)d_in[0];
    const int*   ei = (const int*)d_in[1];  // int32 edge_index
    const float* W1 = (const float*)d_in[2];
    const float* b1 = (const float*)d_in[3];
    const float* W2 = (const float*)d_in[4];
    const float* b2 = (const float*)d_in[5];
    const float* Wc = (const float*)d_in[6];
    const float* bc = (const float*)d_in[7];
    float* out = (float*)d_out;

    const int n = in_sizes[0] / 128;   // 100000
    const int E = in_sizes[1] / 2;     // 600000

    const int* src = ei;
    const int* dst = ei + (size_t)E;

    const int nb = (n + SCAN_TILE - 1) / SCAN_TILE;   // 49 blocks (must be <=256)

    // ws layout (4B elems): dinv[n] | deg/cursor[n] | row_ptr[n+1] | col[E]
    //                       | bsum[256] | bufA[64n] | bufB[64n]    (~54.8 MB)
    float* dinv    = (float*)d_ws;
    int*   deg     = (int*)d_ws + n;
    int*   row_ptr = (int*)d_ws + 2 * (size_t)n;
    int*   col     = row_ptr + (n + 1);
    int*   bsum    = col + E;
    float* bufA    = (float*)(bsum + 256);     // h1, then h2
    float* bufB    = bufA + (size_t)n * 64;    // hr1

    hipMemsetAsync(deg, 0, (size_t)n * 4, stream);
    count_kernel<<<(E + 255) / 256, 256, 0, stream>>>(dst, deg, E);
    tile_reduce_kernel<<<nb, SCAN_THREADS, 0, stream>>>(deg, bsum, n);
    scan_bsums_kernel<<<1, SCAN_THREADS, 0, stream>>>(bsum, row_ptr, nb, n);
    tile_apply_kernel<<<nb, SCAN_THREADS, 0, stream>>>(deg, bsum, row_ptr, dinv, n);
    fill_kernel<<<(E + 255) / 256, 256, 0, stream>>>(src, dst, deg, col, E);

    const int gemm_grid = (n + 127) / 128;   // 128 nodes per 256-thread block

    // Layer 1
    gemm_kernel<128, 64><<<gemm_grid, 256, 0, stream>>>(x, W1, bufA, n);
    agg_relu_kernel<64><<<(n * 16 + 255) / 256, 256, 0, stream>>>(row_ptr, col, dinv,
                                                                  bufA, b1, bufB, n);
    // Layer 2 + head
    gemm_kernel<64, 32><<<gemm_grid, 256, 0, stream>>>(bufB, W2, bufA, n);
    agg_final_kernel<<<(n * 8 + 255) / 256, 256, 0, stream>>>(row_ptr, col, dinv,
                                                              bufA, b2, Wc, bc, out, n);
}

// Round 12
// 268.949 us; speedup vs baseline: 1.0507x; 1.0249x over previous
//
#include <hip/hip_runtime.h>

// ---------------------------------------------------------------------------
// HabitatGNN: 2-layer GCN (self loops, symmetric norm) + linear head.
// x:[N,128] f32, edge_index:[2,E] int32, W1:[128,64], W2:[64,32], Wc:[32,1].
//
// R5:  atomic scatter = 75% of runtime -> CSR + gather.
// R6:  single-block scan = 51% -> 3-phase device-wide scan.
// R7:  quad-per-node gemm: 70->44us.
// R8-R11: occupancy/reg-block/scalar-W levers all ~44-56us. Model: any
//      lane=node mapping pays ~4B operand per MAC (3.3GB) -> ~45us floor.
// R12: micro-tiled GEMM: TMxTN outputs/thread (8x4 / 4x4), W+X in LDS,
//      1.5B/MAC -> 1.23GB LDS -> ~18us floor, 32-acc ILP, 12 waves/CU.
// ---------------------------------------------------------------------------

#define SCAN_THREADS 256
#define SCAN_PER_T   8
#define SCAN_TILE    (SCAN_THREADS * SCAN_PER_T)   // 2048 elements per block

__global__ __launch_bounds__(256) void count_kernel(const int* __restrict__ dst,
                                                    int* __restrict__ deg, int E) {
    int e = blockIdx.x * blockDim.x + threadIdx.x;
    if (e < E) atomicAdd(&deg[dst[e]], 1);
}

// Phase A: per-block tile sum.
__global__ __launch_bounds__(SCAN_THREADS) void tile_reduce_kernel(const int* __restrict__ deg,
                                                                   int* __restrict__ bsum,
                                                                   int n) {
    __shared__ int s[SCAN_THREADS];
    int t = threadIdx.x;
    int gbase = blockIdx.x * SCAN_TILE + t * SCAN_PER_T;
    int local = 0;
#pragma unroll
    for (int k = 0; k < SCAN_PER_T; ++k) {
        int i = gbase + k;
        if (i < n) local += deg[i];
    }
    s[t] = local;
    __syncthreads();
    for (int off = SCAN_THREADS / 2; off > 0; off >>= 1) {
        if (t < off) s[t] += s[t + off];
        __syncthreads();
    }
    if (t == 0) bsum[blockIdx.x] = s[0];
}

// Phase B: scan the <=256 block sums (exclusive, in place); row_ptr[n] = total.
__global__ __launch_bounds__(SCAN_THREADS) void scan_bsums_kernel(int* __restrict__ bsum,
                                                                  int* __restrict__ row_ptr,
                                                                  int nb, int n) {
    __shared__ int s[SCAN_THREADS];
    int t = threadIdx.x;
    s[t] = (t < nb) ? bsum[t] : 0;
    __syncthreads();
    for (int off = 1; off < SCAN_THREADS; off <<= 1) {
        int v = (t >= off) ? s[t - off] : 0;
        __syncthreads();
        s[t] += v;
        __syncthreads();
    }
    if (t < nb) bsum[t] = (t == 0) ? 0 : s[t - 1];   // exclusive prefix
    if (t == 0) row_ptr[n] = s[nb - 1];              // == E
}

// Phase C: re-scan tile, add block prefix; write row_ptr, cursor, dinv.
__global__ __launch_bounds__(SCAN_THREADS) void tile_apply_kernel(int* __restrict__ deg,
                                                                  const int* __restrict__ bsum,
                                                                  int* __restrict__ row_ptr,
                                                                  float* __restrict__ dinv,
                                                                  int n) {
    __shared__ int s[SCAN_THREADS];
    int t = threadIdx.x;
    int gbase = blockIdx.x * SCAN_TILE + t * SCAN_PER_T;

    int d[SCAN_PER_T];
    int inc[SCAN_PER_T];
    int run = 0;
#pragma unroll
    for (int k = 0; k < SCAN_PER_T; ++k) {
        int i = gbase + k;
        d[k] = (i < n) ? deg[i] : 0;
        run += d[k];
        inc[k] = run;                      // inclusive within thread
    }
    s[t] = run;
    __syncthreads();
    for (int off = 1; off < SCAN_THREADS; off <<= 1) {
        int v = (t >= off) ? s[t - off] : 0;
        __syncthreads();
        s[t] += v;
        __syncthreads();
    }
    int base = bsum[blockIdx.x] + ((t == 0) ? 0 : s[t - 1]);
#pragma unroll
    for (int k = 0; k < SCAN_PER_T; ++k) {
        int i = gbase + k;
        if (i < n) {
            int ex = base + inc[k] - d[k];          // exclusive prefix for i
            row_ptr[i] = ex;
            deg[i] = ex;                            // fill cursor
            dinv[i] = rsqrtf((float)(d[k] + 1));    // +1 = self loop
        }
    }
}

__global__ __launch_bounds__(256) void fill_kernel(const int* __restrict__ src,
                                                   const int* __restrict__ dst,
                                                   int* __restrict__ cursor,
                                                   int* __restrict__ col, int E) {
    int e = blockIdx.x * blockDim.x + threadIdx.x;
    if (e < E) {
        int pos = atomicAdd(&cursor[dst[e]], 1);
        col[pos] = src[e];
    }
}

// Micro-tiled GEMM: H[n,OUT] = X[n,IN] @ W[IN,OUT].
// Block: BM nodes x full OUT, 256 threads, thread tile TM x TN (TN==4).
// W fully in LDS; X staged per BK=32 k-tile at stride 33 (conflict-free).
// Per k-step: TM b32 + 1 b128 LDS reads for TM*TN MACs.
template <int IN, int OUT, int BM, int TM, int TN>
__global__ __launch_bounds__(256) void gemm_tiled(const float* __restrict__ X,
                                                  const float* __restrict__ W,
                                                  float* __restrict__ H, int n) {
    constexpr int BK = 32;
    constexpr int XST = BK + 1;              // 33: conflict-free rows
    constexpr int NTX = OUT / TN;            // threads along OUT
    constexpr int NF4 = BM * BK / 4;         // float4s per X tile
    static_assert(NTX * (BM / TM) == 256, "thread mapping");

    __shared__ float Ws[IN * OUT];
    __shared__ float Xs[BM * XST];

    const int t = threadIdx.x;
    for (int i = t; i < IN * OUT / 4; i += 256)
        ((float4*)Ws)[i] = ((const float4*)W)[i];

    const int node0 = blockIdx.x * BM;
    const int tx = t % NTX;
    const int ty = t / NTX;
    const int row0 = ty * TM;
    const int jb = tx * TN;

    float acc[TM][TN];
#pragma unroll
    for (int i = 0; i < TM; ++i)
#pragma unroll
        for (int j = 0; j < TN; ++j) acc[i][j] = 0.f;

    for (int kt = 0; kt < IN / BK; ++kt) {
        __syncthreads();                       // previous tile consumed (+Ws @kt=0)
        for (int f = t; f < NF4; f += 256) {
            int nd = f >> 3;                   // BK/4 = 8 float4s per row
            int kq = f & 7;
            float4 val = make_float4(0.f, 0.f, 0.f, 0.f);
            if (node0 + nd < n)
                val = *(const float4*)(X + (size_t)(node0 + nd) * IN + kt * BK + kq * 4);
            float* p = Xs + nd * XST + kq * 4;
            p[0] = val.x; p[1] = val.y; p[2] = val.z; p[3] = val.w;
        }
        __syncthreads();

#pragma unroll 4
        for (int k = 0; k < BK; ++k) {
            float xv[TM];
#pragma unroll
            for (int i = 0; i < TM; ++i) xv[i] = Xs[(row0 + i) * XST + k];
            float4 wv = *(const float4*)(Ws + (size_t)(kt * BK + k) * OUT + jb);
#pragma unroll
            for (int i = 0; i < TM; ++i) {
                acc[i][0] += xv[i] * wv.x;
                acc[i][1] += xv[i] * wv.y;
                acc[i][2] += xv[i] * wv.z;
                acc[i][3] += xv[i] * wv.w;
            }
        }
    }

#pragma unroll
    for (int i = 0; i < TM; ++i) {
        int node = node0 + row0 + i;
        if (node < n)
            *(float4*)(H + (size_t)node * OUT + jb) =
                make_float4(acc[i][0], acc[i][1], acc[i][2], acc[i][3]);
    }
}

// Gather aggregation, F/4 threads per node, each owns a float4 column.
// OUT[i] = relu(dinv[i]*Sum dinv[s]*H[s] + dinv[i]^2*H[i] + b)
template <int F>
__global__ __launch_bounds__(256) void agg_relu_kernel(const int* __restrict__ row_ptr,
                                                       const int* __restrict__ col,
                                                       const float* __restrict__ dinv,
                                                       const float* __restrict__ H,
                                                       const float* __restrict__ b,
                                                       float* __restrict__ OUT, int n) {
    constexpr int TPE = F / 4;
    int t = blockIdx.x * blockDim.x + threadIdx.x;
    int node = t / TPE;
    int c = t % TPE;
    if (node >= n) return;
    int rs = row_ptr[node], re = row_ptr[node + 1];
    float di = dinv[node];
    float4 acc = make_float4(0.f, 0.f, 0.f, 0.f);
    int e = rs;
    for (; e + 1 < re; e += 2) {
        int s0 = col[e], s1 = col[e + 1];
        float w0 = dinv[s0], w1 = dinv[s1];
        float4 v0 = *(const float4*)(H + (size_t)s0 * F + c * 4);
        float4 v1 = *(const float4*)(H + (size_t)s1 * F + c * 4);
        acc.x += w0 * v0.x + w1 * v1.x;
        acc.y += w0 * v0.y + w1 * v1.y;
        acc.z += w0 * v0.z + w1 * v1.z;
        acc.w += w0 * v0.w + w1 * v1.w;
    }
    if (e < re) {
        int s0 = col[e];
        float w0 = dinv[s0];
        float4 v0 = *(const float4*)(H + (size_t)s0 * F + c * 4);
        acc.x += w0 * v0.x; acc.y += w0 * v0.y;
        acc.z += w0 * v0.z; acc.w += w0 * v0.w;
    }
    float4 hs = *(const float4*)(H + (size_t)node * F + c * 4);
    float4 bb = *(const float4*)(b + c * 4);
    float d2 = di * di;
    float4 r;
    r.x = di * acc.x + d2 * hs.x + bb.x;
    r.y = di * acc.y + d2 * hs.y + bb.y;
    r.z = di * acc.z + d2 * hs.z + bb.z;
    r.w = di * acc.w + d2 * hs.w + bb.w;
    r.x = r.x > 0.f ? r.x : 0.f;
    r.y = r.y > 0.f ? r.y : 0.f;
    r.z = r.z > 0.f ? r.z : 0.f;
    r.w = r.w > 0.f ? r.w : 0.f;
    *(float4*)(OUT + (size_t)node * F + c * 4) = r;
}

// Layer-2 aggregation fused with the classifier head:
// out[i] = relu(agg(H2)[i] + b2) . Wc + bc  (8 lanes per node, shfl reduce)
__global__ __launch_bounds__(256) void agg_final_kernel(const int* __restrict__ row_ptr,
                                                        const int* __restrict__ col,
                                                        const float* __restrict__ dinv,
                                                        const float* __restrict__ H,
                                                        const float* __restrict__ b2,
                                                        const float* __restrict__ Wc,
                                                        const float* __restrict__ bc,
                                                        float* __restrict__ out, int n) {
    constexpr int F = 32, TPE = 8;
    int t = blockIdx.x * blockDim.x + threadIdx.x;
    int node = t / TPE;
    int c = t % TPE;
    if (node >= n) return;
    int rs = row_ptr[node], re = row_ptr[node + 1];
    float di = dinv[node];
    float4 acc = make_float4(0.f, 0.f, 0.f, 0.f);
    int e = rs;
    for (; e + 1 < re; e += 2) {
        int s0 = col[e], s1 = col[e + 1];
        float w0 = dinv[s0], w1 = dinv[s1];
        float4 v0 = *(const float4*)(H + (size_t)s0 * F + c * 4);
        float4 v1 = *(const float4*)(H + (size_t)s1 * F + c * 4);
        acc.x += w0 * v0.x + w1 * v1.x;
        acc.y += w0 * v0.y + w1 * v1.y;
        acc.z += w0 * v0.z + w1 * v1.z;
        acc.w += w0 * v0.w + w1 * v1.w;
    }
    if (e < re) {
        int s0 = col[e];
        float w0 = dinv[s0];
        float4 v0 = *(const float4*)(H + (size_t)s0 * F + c * 4);
        acc.x += w0 * v0.x; acc.y += w0 * v0.y;
        acc.z += w0 * v0.z; acc.w += w0 * v0.w;
    }
    float4 hs = *(const float4*)(H + (size_t)node * F + c * 4);
    float4 bb = *(const float4*)(b2 + c * 4);
    float4 wc = *(const float4*)(Wc + c * 4);
    float d2 = di * di;
    float4 r;
    r.x = di * acc.x + d2 * hs.x + bb.x;
    r.y = di * acc.y + d2 * hs.y + bb.y;
    r.z = di * acc.z + d2 * hs.z + bb.z;
    r.w = di * acc.w + d2 * hs.w + bb.w;
    float dot = (r.x > 0.f ? r.x : 0.f) * wc.x + (r.y > 0.f ? r.y : 0.f) * wc.y +
                (r.z > 0.f ? r.z : 0.f) * wc.z + (r.w > 0.f ? r.w : 0.f) * wc.w;
    dot += __shfl_xor(dot, 1, 8);
    dot += __shfl_xor(dot, 2, 8);
    dot += __shfl_xor(dot, 4, 8);
    if (c == 0) out[node] = dot + bc[0];
}

extern "C" void kernel_launch(void* const* d_in, const int* in_sizes, int n_in,
                              void* d_out, int out_size, void* d_ws, size_t ws_size,
                              hipStream_t stream) {
    const float* x  = (const float*)d_in[0];
    const int*   ei = (const int*)d_in[1];  // int32 edge_index
    const float* W1 = (const float*)d_in[2];
    const float* b1 = (const float*)d_in[3];
    const float* W2 = (const float*)d_in[4];
    const float* b2 = (const float*)d_in[5];
    const float* Wc = (const float*)d_in[6];
    const float* bc = (const float*)d_in[7];
    float* out = (float*)d_out;

    const int n = in_sizes[0] / 128;   // 100000
    const int E = in_sizes[1] / 2;     // 600000

    const int* src = ei;
    const int* dst = ei + (size_t)E;

    const int nb = (n + SCAN_TILE - 1) / SCAN_TILE;   // 49 blocks (must be <=256)

    // ws layout (4B elems): dinv[n] | deg/cursor[n] | row_ptr[n+1] | col[E]
    //                       | bsum[256] | bufA[64n] | bufB[64n]    (~54.8 MB)
    float* dinv    = (float*)d_ws;
    int*   deg     = (int*)d_ws + n;
    int*   row_ptr = (int*)d_ws + 2 * (size_t)n;
    int*   col     = row_ptr + (n + 1);
    int*   bsum    = col + E;
    float* bufA    = (float*)(bsum + 256);     // h1, then h2
    float* bufB    = bufA + (size_t)n * 64;    // hr1

    hipMemsetAsync(deg, 0, (size_t)n * 4, stream);
    count_kernel<<<(E + 255) / 256, 256, 0, stream>>>(dst, deg, E);
    tile_reduce_kernel<<<nb, SCAN_THREADS, 0, stream>>>(deg, bsum, n);
    scan_bsums_kernel<<<1, SCAN_THREADS, 0, stream>>>(bsum, row_ptr, nb, n);
    tile_apply_kernel<<<nb, SCAN_THREADS, 0, stream>>>(deg, bsum, row_ptr, dinv, n);
    fill_kernel<<<(E + 255) / 256, 256, 0, stream>>>(src, dst, deg, col, E);

    const int gemm_grid = (n + 127) / 128;   // BM=128 nodes per block

    // Layer 1: TM=8, TN=4 (16x16 threads)
    gemm_tiled<128, 64, 128, 8, 4><<<gemm_grid, 256, 0, stream>>>(x, W1, bufA, n);
    agg_relu_kernel<64><<<(n * 16 + 255) / 256, 256, 0, stream>>>(row_ptr, col, dinv,
                                                                  bufA, b1, bufB, n);
    // Layer 2 + head: TM=4, TN=4 (8x32 threads)
    gemm_tiled<64, 32, 128, 4, 4><<<gemm_grid, 256, 0, stream>>>(bufB, W2, bufA, n);
    agg_final_kernel<<<(n * 8 + 255) / 256, 256, 0, stream>>>(row_ptr, col, dinv,
                                                              bufA, b2, Wc, bc, out, n);
}

// Round 13
// 266.975 us; speedup vs baseline: 1.0585x; 1.0074x over previous
//
#include <hip/hip_runtime.h>

// ---------------------------------------------------------------------------
// HabitatGNN: 2-layer GCN (self loops, symmetric norm) + linear head.
// x:[N,128] f32, edge_index:[2,E] int32, W1:[128,64], W2:[64,32], Wc:[32,1].
//
// R5:  atomic scatter = 75% of runtime -> CSR + gather.
// R6:  single-block scan = 51% -> 3-phase device-wide scan.
// R7-R12: gemm variants all 44-56us. R12 counters: hbm 951GB/s == in-flight
//      bytes (4 ldg x 12 waves) / latency -> FETCH-CONCURRENCY-bound; plus
//      9 LDS instr per 32 FMAs steals issue.
// R13: (a) software double-buffer: next tile's global loads issued to regs
//      BEFORE computing current tile (latency hides under compute);
//      (b) transposed Xs[k][node] stride 132: X reads = 2 ds_read_b128
//      per k (was 8 b32), conflict-free.
// ---------------------------------------------------------------------------

#define SCAN_THREADS 256
#define SCAN_PER_T   8
#define SCAN_TILE    (SCAN_THREADS * SCAN_PER_T)   // 2048 elements per block

__global__ __launch_bounds__(256) void count_kernel(const int* __restrict__ dst,
                                                    int* __restrict__ deg, int E) {
    int e = blockIdx.x * blockDim.x + threadIdx.x;
    if (e < E) atomicAdd(&deg[dst[e]], 1);
}

// Phase A: per-block tile sum.
__global__ __launch_bounds__(SCAN_THREADS) void tile_reduce_kernel(const int* __restrict__ deg,
                                                                   int* __restrict__ bsum,
                                                                   int n) {
    __shared__ int s[SCAN_THREADS];
    int t = threadIdx.x;
    int gbase = blockIdx.x * SCAN_TILE + t * SCAN_PER_T;
    int local = 0;
#pragma unroll
    for (int k = 0; k < SCAN_PER_T; ++k) {
        int i = gbase + k;
        if (i < n) local += deg[i];
    }
    s[t] = local;
    __syncthreads();
    for (int off = SCAN_THREADS / 2; off > 0; off >>= 1) {
        if (t < off) s[t] += s[t + off];
        __syncthreads();
    }
    if (t == 0) bsum[blockIdx.x] = s[0];
}

// Phase B: scan the <=256 block sums (exclusive, in place); row_ptr[n] = total.
__global__ __launch_bounds__(SCAN_THREADS) void scan_bsums_kernel(int* __restrict__ bsum,
                                                                  int* __restrict__ row_ptr,
                                                                  int nb, int n) {
    __shared__ int s[SCAN_THREADS];
    int t = threadIdx.x;
    s[t] = (t < nb) ? bsum[t] : 0;
    __syncthreads();
    for (int off = 1; off < SCAN_THREADS; off <<= 1) {
        int v = (t >= off) ? s[t - off] : 0;
        __syncthreads();
        s[t] += v;
        __syncthreads();
    }
    if (t < nb) bsum[t] = (t == 0) ? 0 : s[t - 1];   // exclusive prefix
    if (t == 0) row_ptr[n] = s[nb - 1];              // == E
}

// Phase C: re-scan tile, add block prefix; write row_ptr, cursor, dinv.
__global__ __launch_bounds__(SCAN_THREADS) void tile_apply_kernel(int* __restrict__ deg,
                                                                  const int* __restrict__ bsum,
                                                                  int* __restrict__ row_ptr,
                                                                  float* __restrict__ dinv,
                                                                  int n) {
    __shared__ int s[SCAN_THREADS];
    int t = threadIdx.x;
    int gbase = blockIdx.x * SCAN_TILE + t * SCAN_PER_T;

    int d[SCAN_PER_T];
    int inc[SCAN_PER_T];
    int run = 0;
#pragma unroll
    for (int k = 0; k < SCAN_PER_T; ++k) {
        int i = gbase + k;
        d[k] = (i < n) ? deg[i] : 0;
        run += d[k];
        inc[k] = run;                      // inclusive within thread
    }
    s[t] = run;
    __syncthreads();
    for (int off = 1; off < SCAN_THREADS; off <<= 1) {
        int v = (t >= off) ? s[t - off] : 0;
        __syncthreads();
        s[t] += v;
        __syncthreads();
    }
    int base = bsum[blockIdx.x] + ((t == 0) ? 0 : s[t - 1]);
#pragma unroll
    for (int k = 0; k < SCAN_PER_T; ++k) {
        int i = gbase + k;
        if (i < n) {
            int ex = base + inc[k] - d[k];          // exclusive prefix for i
            row_ptr[i] = ex;
            deg[i] = ex;                            // fill cursor
            dinv[i] = rsqrtf((float)(d[k] + 1));    // +1 = self loop
        }
    }
}

__global__ __launch_bounds__(256) void fill_kernel(const int* __restrict__ src,
                                                   const int* __restrict__ dst,
                                                   int* __restrict__ cursor,
                                                   int* __restrict__ col, int E) {
    int e = blockIdx.x * blockDim.x + threadIdx.x;
    if (e < E) {
        int pos = atomicAdd(&cursor[dst[e]], 1);
        col[pos] = src[e];
    }
}

// Double-buffered, transposed-X micro-tiled GEMM: H[n,OUT] = X[n,IN] @ W.
// Block: BM=128 nodes x full OUT, 256 threads, thread tile TM x TN (TN=4).
// Xs[buf][k][node] stride 132 (b128-aligned; conflict-free reads).
// Per k-step: TM/4+... = 2 (TM=8) or 1 (TM=4) ds_read_b128 for X + 1 for W
// per TM*TN FMAs. Next tile's 4 global float4 loads are in flight during
// the current tile's compute.
template <int IN, int OUT, int BM, int TM, int TN>
__global__ __launch_bounds__(256) void gemm_tiled(const float* __restrict__ X,
                                                  const float* __restrict__ W,
                                                  float* __restrict__ H, int n) {
    constexpr int BK = 32;
    constexpr int S = 132;                   // transposed row stride (words)
    constexpr int NTX = OUT / TN;            // threads along OUT
    constexpr int NKT = IN / BK;
    static_assert(NTX * (BM / TM) == 256, "thread mapping");

    __shared__ float Ws[IN * OUT];
    __shared__ float Xs[2][BK * S];

    const int t = threadIdx.x;
    for (int i = t; i < IN * OUT / 4; i += 256)
        ((float4*)Ws)[i] = ((const float4*)W)[i];

    const int node0 = blockIdx.x * BM;
    const int tx = t % NTX;
    const int ty = t / NTX;
    const int row0 = ty * TM;
    const int jb = tx * TN;

    // staging coords: 4 float4s per thread per tile
    const int snd = t >> 3;                  // node row 0..31 (x4 via +32*i)
    const int skq = t & 7;                   // k-quad 0..7

    float acc[TM][TN];
#pragma unroll
    for (int i = 0; i < TM; ++i)
#pragma unroll
        for (int j = 0; j < TN; ++j) acc[i][j] = 0.f;

    float4 stg[4];
    // prologue: load tile 0
#pragma unroll
    for (int i = 0; i < 4; ++i) {
        int nd = snd + 32 * i;
        stg[i] = make_float4(0.f, 0.f, 0.f, 0.f);
        if (node0 + nd < n)
            stg[i] = *(const float4*)(X + (size_t)(node0 + nd) * IN + skq * 4);
    }

    int cur = 0;
    for (int kt = 0; kt < NKT; ++kt) {
        // write staged regs -> Xs[cur] (transposed)
#pragma unroll
        for (int i = 0; i < 4; ++i) {
            int nd = snd + 32 * i;
            float* p = Xs[cur] + (skq * 4) * S + nd;
            p[0 * S] = stg[i].x;
            p[1 * S] = stg[i].y;
            p[2 * S] = stg[i].z;
            p[3 * S] = stg[i].w;
        }
        __syncthreads();

        // issue next tile's loads (in flight during compute below)
        if (kt + 1 < NKT) {
#pragma unroll
            for (int i = 0; i < 4; ++i) {
                int nd = snd + 32 * i;
                stg[i] = make_float4(0.f, 0.f, 0.f, 0.f);
                if (node0 + nd < n)
                    stg[i] = *(const float4*)(X + (size_t)(node0 + nd) * IN +
                                              (kt + 1) * BK + skq * 4);
            }
        }

        const float* xb = Xs[cur];
        const float* wb = Ws + (size_t)kt * BK * OUT + jb;
#pragma unroll 4
        for (int k = 0; k < BK; ++k) {
            float4 wv = *(const float4*)(wb + (size_t)k * OUT);
            float xv[TM];
#pragma unroll
            for (int i4 = 0; i4 < TM; i4 += 4) {
                float4 xq = *(const float4*)(xb + k * S + row0 + i4);
                xv[i4 + 0] = xq.x; xv[i4 + 1] = xq.y;
                xv[i4 + 2] = xq.z; xv[i4 + 3] = xq.w;
            }
#pragma unroll
            for (int i = 0; i < TM; ++i) {
                acc[i][0] += xv[i] * wv.x;
                acc[i][1] += xv[i] * wv.y;
                acc[i][2] += xv[i] * wv.z;
                acc[i][3] += xv[i] * wv.w;
            }
        }
        __syncthreads();   // all waves done reading Xs[cur] before next write
        cur ^= 1;
    }

#pragma unroll
    for (int i = 0; i < TM; ++i) {
        int node = node0 + row0 + i;
        if (node < n)
            *(float4*)(H + (size_t)node * OUT + jb) =
                make_float4(acc[i][0], acc[i][1], acc[i][2], acc[i][3]);
    }
}

// Gather aggregation, F/4 threads per node, each owns a float4 column.
// OUT[i] = relu(dinv[i]*Sum dinv[s]*H[s] + dinv[i]^2*H[i] + b)
template <int F>
__global__ __launch_bounds__(256) void agg_relu_kernel(const int* __restrict__ row_ptr,
                                                       const int* __restrict__ col,
                                                       const float* __restrict__ dinv,
                                                       const float* __restrict__ H,
                                                       const float* __restrict__ b,
                                                       float* __restrict__ OUT, int n) {
    constexpr int TPE = F / 4;
    int t = blockIdx.x * blockDim.x + threadIdx.x;
    int node = t / TPE;
    int c = t % TPE;
    if (node >= n) return;
    int rs = row_ptr[node], re = row_ptr[node + 1];
    float di = dinv[node];
    float4 acc = make_float4(0.f, 0.f, 0.f, 0.f);
    int e = rs;
    for (; e + 1 < re; e += 2) {
        int s0 = col[e], s1 = col[e + 1];
        float w0 = dinv[s0], w1 = dinv[s1];
        float4 v0 = *(const float4*)(H + (size_t)s0 * F + c * 4);
        float4 v1 = *(const float4*)(H + (size_t)s1 * F + c * 4);
        acc.x += w0 * v0.x + w1 * v1.x;
        acc.y += w0 * v0.y + w1 * v1.y;
        acc.z += w0 * v0.z + w1 * v1.z;
        acc.w += w0 * v0.w + w1 * v1.w;
    }
    if (e < re) {
        int s0 = col[e];
        float w0 = dinv[s0];
        float4 v0 = *(const float4*)(H + (size_t)s0 * F + c * 4);
        acc.x += w0 * v0.x; acc.y += w0 * v0.y;
        acc.z += w0 * v0.z; acc.w += w0 * v0.w;
    }
    float4 hs = *(const float4*)(H + (size_t)node * F + c * 4);
    float4 bb = *(const float4*)(b + c * 4);
    float d2 = di * di;
    float4 r;
    r.x = di * acc.x + d2 * hs.x + bb.x;
    r.y = di * acc.y + d2 * hs.y + bb.y;
    r.z = di * acc.z + d2 * hs.z + bb.z;
    r.w = di * acc.w + d2 * hs.w + bb.w;
    r.x = r.x > 0.f ? r.x : 0.f;
    r.y = r.y > 0.f ? r.y : 0.f;
    r.z = r.z > 0.f ? r.z : 0.f;
    r.w = r.w > 0.f ? r.w : 0.f;
    *(float4*)(OUT + (size_t)node * F + c * 4) = r;
}

// Layer-2 aggregation fused with the classifier head:
// out[i] = relu(agg(H2)[i] + b2) . Wc + bc  (8 lanes per node, shfl reduce)
__global__ __launch_bounds__(256) void agg_final_kernel(const int* __restrict__ row_ptr,
                                                        const int* __restrict__ col,
                                                        const float* __restrict__ dinv,
                                                        const float* __restrict__ H,
                                                        const float* __restrict__ b2,
                                                        const float* __restrict__ Wc,
                                                        const float* __restrict__ bc,
                                                        float* __restrict__ out, int n) {
    constexpr int F = 32, TPE = 8;
    int t = blockIdx.x * blockDim.x + threadIdx.x;
    int node = t / TPE;
    int c = t % TPE;
    if (node >= n) return;
    int rs = row_ptr[node], re = row_ptr[node + 1];
    float di = dinv[node];
    float4 acc = make_float4(0.f, 0.f, 0.f, 0.f);
    int e = rs;
    for (; e + 1 < re; e += 2) {
        int s0 = col[e], s1 = col[e + 1];
        float w0 = dinv[s0], w1 = dinv[s1];
        float4 v0 = *(const float4*)(H + (size_t)s0 * F + c * 4);
        float4 v1 = *(const float4*)(H + (size_t)s1 * F + c * 4);
        acc.x += w0 * v0.x + w1 * v1.x;
        acc.y += w0 * v0.y + w1 * v1.y;
        acc.z += w0 * v0.z + w1 * v1.z;
        acc.w += w0 * v0.w + w1 * v1.w;
    }
    if (e < re) {
        int s0 = col[e];
        float w0 = dinv[s0];
        float4 v0 = *(const float4*)(H + (size_t)s0 * F + c * 4);
        acc.x += w0 * v0.x; acc.y += w0 * v0.y;
        acc.z += w0 * v0.z; acc.w += w0 * v0.w;
    }
    float4 hs = *(const float4*)(H + (size_t)node * F + c * 4);
    float4 bb = *(const float4*)(b2 + c * 4);
    float4 wc = *(const float4*)(Wc + c * 4);
    float d2 = di * di;
    float4 r;
    r.x = di * acc.x + d2 * hs.x + bb.x;
    r.y = di * acc.y + d2 * hs.y + bb.y;
    r.z = di * acc.z + d2 * hs.z + bb.z;
    r.w = di * acc.w + d2 * hs.w + bb.w;
    float dot = (r.x > 0.f ? r.x : 0.f) * wc.x + (r.y > 0.f ? r.y : 0.f) * wc.y +
                (r.z > 0.f ? r.z : 0.f) * wc.z + (r.w > 0.f ? r.w : 0.f) * wc.w;
    dot += __shfl_xor(dot, 1, 8);
    dot += __shfl_xor(dot, 2, 8);
    dot += __shfl_xor(dot, 4, 8);
    if (c == 0) out[node] = dot + bc[0];
}

extern "C" void kernel_launch(void* const* d_in, const int* in_sizes, int n_in,
                              void* d_out, int out_size, void* d_ws, size_t ws_size,
                              hipStream_t stream) {
    const float* x  = (const float*)d_in[0];
    const int*   ei = (const int*)d_in[1];  // int32 edge_index
    const float* W1 = (const float*)d_in[2];
    const float* b1 = (const float*)d_in[3];
    const float* W2 = (const float*)d_in[4];
    const float* b2 = (const float*)d_in[5];
    const float* Wc = (const float*)d_in[6];
    const float* bc = (const float*)d_in[7];
    float* out = (float*)d_out;

    const int n = in_sizes[0] / 128;   // 100000
    const int E = in_sizes[1] / 2;     // 600000

    const int* src = ei;
    const int* dst = ei + (size_t)E;

    const int nb = (n + SCAN_TILE - 1) / SCAN_TILE;   // 49 blocks (must be <=256)

    // ws layout (4B elems): dinv[n] | deg/cursor[n] | row_ptr[n+1] | col[E]
    //                       | bsum[256] | bufA[64n] | bufB[64n]    (~54.8 MB)
    float* dinv    = (float*)d_ws;
    int*   deg     = (int*)d_ws + n;
    int*   row_ptr = (int*)d_ws + 2 * (size_t)n;
    int*   col     = row_ptr + (n + 1);
    int*   bsum    = col + E;
    float* bufA    = (float*)(bsum + 256);     // h1, then h2
    float* bufB    = bufA + (size_t)n * 64;    // hr1

    hipMemsetAsync(deg, 0, (size_t)n * 4, stream);
    count_kernel<<<(E + 255) / 256, 256, 0, stream>>>(dst, deg, E);
    tile_reduce_kernel<<<nb, SCAN_THREADS, 0, stream>>>(deg, bsum, n);
    scan_bsums_kernel<<<1, SCAN_THREADS, 0, stream>>>(bsum, row_ptr, nb, n);
    tile_apply_kernel<<<nb, SCAN_THREADS, 0, stream>>>(deg, bsum, row_ptr, dinv, n);
    fill_kernel<<<(E + 255) / 256, 256, 0, stream>>>(src, dst, deg, col, E);

    const int gemm_grid = (n + 127) / 128;   // BM=128 nodes per block

    // Layer 1: TM=8, TN=4 (16 threads along OUT x 16 node groups)
    gemm_tiled<128, 64, 128, 8, 4><<<gemm_grid, 256, 0, stream>>>(x, W1, bufA, n);
    agg_relu_kernel<64><<<(n * 16 + 255) / 256, 256, 0, stream>>>(row_ptr, col, dinv,
                                                                  bufA, b1, bufB, n);
    // Layer 2 + head: TM=4, TN=4 (8 threads along OUT x 32 node groups)
    gemm_tiled<64, 32, 128, 4, 4><<<gemm_grid, 256, 0, stream>>>(bufB, W2, bufA, n);
    agg_final_kernel<<<(n * 8 + 255) / 256, 256, 0, stream>>>(row_ptr, col, dinv,
                                                              bufA, b2, Wc, bc, out, n);
}

// Round 15
// 266.458 us; speedup vs baseline: 1.0606x; 1.0019x over previous
//
#include <hip/hip_runtime.h>

// ---------------------------------------------------------------------------
// HabitatGNN: 2-layer GCN (self loops, symmetric norm) + linear head.
// x:[N,128] f32, edge_index:[2,E] int32, W1:[128,64], W2:[64,32], Wc:[32,1].
//
// R5:  atomic scatter = 75% of runtime -> CSR + gather.
// R6:  single-block scan = 51% -> 3-phase device-wide scan.
// R7-R13: gemm 70->39.6us (micro-tile + dbuf + transposed Xs). R13 reveal:
//      top-5 clogged by harness 256MB ws-poison (40us); ~100us fixed
//      overhead (poison+restore+gaps). Remaining: gemm1 39.6, agg_* < 39.
// R14: (a) gemm prefetch depth 2 (fetch-concurrency was 950GB/s ceiling);
//      (b) dinv[src] folded into gemm epilogue (H' = dinv*H) -- kills the
//      16x-redundant dinv gather in agg inner loops;
//      (c) agg 4-way edge unroll (gather ILP).
// ---------------------------------------------------------------------------

#define SCAN_THREADS 256
#define SCAN_PER_T   8
#define SCAN_TILE    (SCAN_THREADS * SCAN_PER_T)   // 2048 elements per block

__global__ __launch_bounds__(256) void count_kernel(const int* __restrict__ dst,
                                                    int* __restrict__ deg, int E) {
    int e = blockIdx.x * blockDim.x + threadIdx.x;
    if (e < E) atomicAdd(&deg[dst[e]], 1);
}

__global__ __launch_bounds__(SCAN_THREADS) void tile_reduce_kernel(const int* __restrict__ deg,
                                                                   int* __restrict__ bsum,
                                                                   int n) {
    __shared__ int s[SCAN_THREADS];
    int t = threadIdx.x;
    int gbase = blockIdx.x * SCAN_TILE + t * SCAN_PER_T;
    int local = 0;
#pragma unroll
    for (int k = 0; k < SCAN_PER_T; ++k) {
        int i = gbase + k;
        if (i < n) local += deg[i];
    }
    s[t] = local;
    __syncthreads();
    for (int off = SCAN_THREADS / 2; off > 0; off >>= 1) {
        if (t < off) s[t] += s[t + off];
        __syncthreads();
    }
    if (t == 0) bsum[blockIdx.x] = s[0];
}

__global__ __launch_bounds__(SCAN_THREADS) void scan_bsums_kernel(int* __restrict__ bsum,
                                                                  int* __restrict__ row_ptr,
                                                                  int nb, int n) {
    __shared__ int s[SCAN_THREADS];
    int t = threadIdx.x;
    s[t] = (t < nb) ? bsum[t] : 0;
    __syncthreads();
    for (int off = 1; off < SCAN_THREADS; off <<= 1) {
        int v = (t >= off) ? s[t - off] : 0;
        __syncthreads();
        s[t] += v;
        __syncthreads();
    }
    if (t < nb) bsum[t] = (t == 0) ? 0 : s[t - 1];   // exclusive prefix
    if (t == 0) row_ptr[n] = s[nb - 1];              // == E
}

__global__ __launch_bounds__(SCAN_THREADS) void tile_apply_kernel(int* __restrict__ deg,
                                                                  const int* __restrict__ bsum,
                                                                  int* __restrict__ row_ptr,
                                                                  float* __restrict__ dinv,
                                                                  int n) {
    __shared__ int s[SCAN_THREADS];
    int t = threadIdx.x;
    int gbase = blockIdx.x * SCAN_TILE + t * SCAN_PER_T;

    int d[SCAN_PER_T];
    int inc[SCAN_PER_T];
    int run = 0;
#pragma unroll
    for (int k = 0; k < SCAN_PER_T; ++k) {
        int i = gbase + k;
        d[k] = (i < n) ? deg[i] : 0;
        run += d[k];
        inc[k] = run;
    }
    s[t] = run;
    __syncthreads();
    for (int off = 1; off < SCAN_THREADS; off <<= 1) {
        int v = (t >= off) ? s[t - off] : 0;
        __syncthreads();
        s[t] += v;
        __syncthreads();
    }
    int base = bsum[blockIdx.x] + ((t == 0) ? 0 : s[t - 1]);
#pragma unroll
    for (int k = 0; k < SCAN_PER_T; ++k) {
        int i = gbase + k;
        if (i < n) {
            int ex = base + inc[k] - d[k];
            row_ptr[i] = ex;
            deg[i] = ex;                            // fill cursor
            dinv[i] = rsqrtf((float)(d[k] + 1));    // +1 = self loop
        }
    }
}

__global__ __launch_bounds__(256) void fill_kernel(const int* __restrict__ src,
                                                   const int* __restrict__ dst,
                                                   int* __restrict__ cursor,
                                                   int* __restrict__ col, int E) {
    int e = blockIdx.x * blockDim.x + threadIdx.x;
    if (e < E) {
        int pos = atomicAdd(&cursor[dst[e]], 1);
        col[pos] = src[e];
    }
}

// Double-buffered (prefetch depth 2), transposed-X micro-tiled GEMM.
// H'[i] = dinv[i] * (X[i] @ W)   -- dinv folded into the epilogue so the
// aggregation's inner loop needs no dinv gather.
template <int IN, int OUT, int BM, int TM, int TN>
__global__ __launch_bounds__(256) void gemm_tiled(const float* __restrict__ X,
                                                  const float* __restrict__ W,
                                                  const float* __restrict__ dinv,
                                                  float* __restrict__ H, int n) {
    constexpr int BK = 32;
    constexpr int S = 132;                   // transposed row stride (words)
    constexpr int NTX = OUT / TN;
    constexpr int NKT = IN / BK;
    static_assert(NTX * (BM / TM) == 256, "thread mapping");

    __shared__ float Ws[IN * OUT];
    __shared__ float Xs[2][BK * S];

    const int t = threadIdx.x;
    for (int i = t; i < IN * OUT / 4; i += 256)
        ((float4*)Ws)[i] = ((const float4*)W)[i];

    const int node0 = blockIdx.x * BM;
    const int tx = t % NTX;
    const int ty = t / NTX;
    const int row0 = ty * TM;
    const int jb = tx * TN;

    const int snd = t >> 3;                  // node row 0..31 (x4 via +32*i)
    const int skq = t & 7;                   // k-quad 0..7

    float acc[TM][TN];
#pragma unroll
    for (int i = 0; i < TM; ++i)
#pragma unroll
        for (int j = 0; j < TN; ++j) acc[i][j] = 0.f;

    float4 stgA[4], stgB[4];
    // prologue: tiles 0 and 1 in flight
#pragma unroll
    for (int i = 0; i < 4; ++i) {
        int nd = snd + 32 * i;
        stgA[i] = make_float4(0.f, 0.f, 0.f, 0.f);
        if (node0 + nd < n)
            stgA[i] = *(const float4*)(X + (size_t)(node0 + nd) * IN + skq * 4);
    }
    if (NKT > 1) {
#pragma unroll
        for (int i = 0; i < 4; ++i) {
            int nd = snd + 32 * i;
            stgB[i] = make_float4(0.f, 0.f, 0.f, 0.f);
            if (node0 + nd < n)
                stgB[i] = *(const float4*)(X + (size_t)(node0 + nd) * IN + BK + skq * 4);
        }
    }

    int cur = 0;
    for (int kt = 0; kt < NKT; ++kt) {
        // write tile kt (alternating reg buffer) -> Xs[cur], transposed
#pragma unroll
        for (int i = 0; i < 4; ++i) {
            int nd = snd + 32 * i;
            float* p = Xs[cur] + (skq * 4) * S + nd;
            float4 v = (kt & 1) ? stgB[i] : stgA[i];
            p[0 * S] = v.x; p[1 * S] = v.y; p[2 * S] = v.z; p[3 * S] = v.w;
        }
        __syncthreads();

        // issue tile kt+2 loads into the just-freed reg buffer
        if (kt + 2 < NKT) {
#pragma unroll
            for (int i = 0; i < 4; ++i) {
                int nd = snd + 32 * i;
                float4 v = make_float4(0.f, 0.f, 0.f, 0.f);
                if (node0 + nd < n)
                    v = *(const float4*)(X + (size_t)(node0 + nd) * IN +
                                         (kt + 2) * BK + skq * 4);
                if (kt & 1) stgB[i] = v; else stgA[i] = v;
            }
        }

        const float* xb = Xs[cur];
        const float* wb = Ws + (size_t)kt * BK * OUT + jb;
#pragma unroll 4
        for (int k = 0; k < BK; ++k) {
            float4 wv = *(const float4*)(wb + (size_t)k * OUT);
            float xv[TM];
#pragma unroll
            for (int i4 = 0; i4 < TM; i4 += 4) {
                float4 xq = *(const float4*)(xb + k * S + row0 + i4);
                xv[i4 + 0] = xq.x; xv[i4 + 1] = xq.y;
                xv[i4 + 2] = xq.z; xv[i4 + 3] = xq.w;
            }
#pragma unroll
            for (int i = 0; i < TM; ++i) {
                acc[i][0] += xv[i] * wv.x;
                acc[i][1] += xv[i] * wv.y;
                acc[i][2] += xv[i] * wv.z;
                acc[i][3] += xv[i] * wv.w;
            }
        }
        __syncthreads();
        cur ^= 1;
    }

#pragma unroll
    for (int i = 0; i < TM; ++i) {
        int node = node0 + row0 + i;
        if (node < n) {
            float di = dinv[node];
            *(float4*)(H + (size_t)node * OUT + jb) =
                make_float4(di * acc[i][0], di * acc[i][1],
                            di * acc[i][2], di * acc[i][3]);
        }
    }
}

// Gather aggregation over prescaled H' (= dinv*H):
// OUT[i] = relu(dinv[i] * (Sum_{s in N(i)} H'[s] + H'[i]) + b)
// 4-way edge unroll for gather ILP; inner loop has no dinv access.
template <int F>
__global__ __launch_bounds__(256) void agg_relu_kernel(const int* __restrict__ row_ptr,
                                                       const int* __restrict__ col,
                                                       const float* __restrict__ dinv,
                                                       const float* __restrict__ H,
                                                       const float* __restrict__ b,
                                                       float* __restrict__ OUT, int n) {
    constexpr int TPE = F / 4;
    int t = blockIdx.x * blockDim.x + threadIdx.x;
    int node = t / TPE;
    int c = t % TPE;
    if (node >= n) return;
    int rs = row_ptr[node], re = row_ptr[node + 1];
    float4 acc = make_float4(0.f, 0.f, 0.f, 0.f);
    int e = rs;
    for (; e + 3 < re; e += 4) {
        int s0 = col[e], s1 = col[e + 1], s2 = col[e + 2], s3 = col[e + 3];
        float4 v0 = *(const float4*)(H + (size_t)s0 * F + c * 4);
        float4 v1 = *(const float4*)(H + (size_t)s1 * F + c * 4);
        float4 v2 = *(const float4*)(H + (size_t)s2 * F + c * 4);
        float4 v3 = *(const float4*)(H + (size_t)s3 * F + c * 4);
        acc.x += (v0.x + v1.x) + (v2.x + v3.x);
        acc.y += (v0.y + v1.y) + (v2.y + v3.y);
        acc.z += (v0.z + v1.z) + (v2.z + v3.z);
        acc.w += (v0.w + v1.w) + (v2.w + v3.w);
    }
    for (; e < re; ++e) {
        int s0 = col[e];
        float4 v0 = *(const float4*)(H + (size_t)s0 * F + c * 4);
        acc.x += v0.x; acc.y += v0.y; acc.z += v0.z; acc.w += v0.w;
    }
    float di = dinv[node];
    float4 hs = *(const float4*)(H + (size_t)node * F + c * 4);
    float4 bb = *(const float4*)(b + c * 4);
    float4 r;
    r.x = di * (acc.x + hs.x) + bb.x;
    r.y = di * (acc.y + hs.y) + bb.y;
    r.z = di * (acc.z + hs.z) + bb.z;
    r.w = di * (acc.w + hs.w) + bb.w;
    r.x = r.x > 0.f ? r.x : 0.f;
    r.y = r.y > 0.f ? r.y : 0.f;
    r.z = r.z > 0.f ? r.z : 0.f;
    r.w = r.w > 0.f ? r.w : 0.f;
    *(float4*)(OUT + (size_t)node * F + c * 4) = r;
}

// Layer-2 aggregation (prescaled H2') fused with the classifier head:
// out[i] = relu(dinv[i]*(Sum H2'[s] + H2'[i]) + b2) . Wc + bc
__global__ __launch_bounds__(256) void agg_final_kernel(const int* __restrict__ row_ptr,
                                                        const int* __restrict__ col,
                                                        const float* __restrict__ dinv,
                                                        const float* __restrict__ H,
                                                        const float* __restrict__ b2,
                                                        const float* __restrict__ Wc,
                                                        const float* __restrict__ bc,
                                                        float* __restrict__ out, int n) {
    constexpr int F = 32, TPE = 8;
    int t = blockIdx.x * blockDim.x + threadIdx.x;
    int node = t / TPE;
    int c = t % TPE;
    if (node >= n) return;
    int rs = row_ptr[node], re = row_ptr[node + 1];
    float4 acc = make_float4(0.f, 0.f, 0.f, 0.f);
    int e = rs;
    for (; e + 3 < re; e += 4) {
        int s0 = col[e], s1 = col[e + 1], s2 = col[e + 2], s3 = col[e + 3];
        float4 v0 = *(const float4*)(H + (size_t)s0 * F + c * 4);
        float4 v1 = *(const float4*)(H + (size_t)s1 * F + c * 4);
        float4 v2 = *(const float4*)(H + (size_t)s2 * F + c * 4);
        float4 v3 = *(const float4*)(H + (size_t)s3 * F + c * 4);
        acc.x += (v0.x + v1.x) + (v2.x + v3.x);
        acc.y += (v0.y + v1.y) + (v2.y + v3.y);
        acc.z += (v0.z + v1.z) + (v2.z + v3.z);
        acc.w += (v0.w + v1.w) + (v2.w + v3.w);
    }
    for (; e < re; ++e) {
        int s0 = col[e];
        float4 v0 = *(const float4*)(H + (size_t)s0 * F + c * 4);
        acc.x += v0.x; acc.y += v0.y; acc.z += v0.z; acc.w += v0.w;
    }
    float di = dinv[node];
    float4 hs = *(const float4*)(H + (size_t)node * F + c * 4);
    float4 bb = *(const float4*)(b2 + c * 4);
    float4 wc = *(const float4*)(Wc + c * 4);
    float4 r;
    r.x = di * (acc.x + hs.x) + bb.x;
    r.y = di * (acc.y + hs.y) + bb.y;
    r.z = di * (acc.z + hs.z) + bb.z;
    r.w = di * (acc.w + hs.w) + bb.w;
    float dot = (r.x > 0.f ? r.x : 0.f) * wc.x + (r.y > 0.f ? r.y : 0.f) * wc.y +
                (r.z > 0.f ? r.z : 0.f) * wc.z + (r.w > 0.f ? r.w : 0.f) * wc.w;
    dot += __shfl_xor(dot, 1, 8);
    dot += __shfl_xor(dot, 2, 8);
    dot += __shfl_xor(dot, 4, 8);
    if (c == 0) out[node] = dot + bc[0];
}

extern "C" void kernel_launch(void* const* d_in, const int* in_sizes, int n_in,
                              void* d_out, int out_size, void* d_ws, size_t ws_size,
                              hipStream_t stream) {
    const float* x  = (const float*)d_in[0];
    const int*   ei = (const int*)d_in[1];  // int32 edge_index
    const float* W1 = (const float*)d_in[2];
    const float* b1 = (const float*)d_in[3];
    const float* W2 = (const float*)d_in[4];
    const float* b2 = (const float*)d_in[5];
    const float* Wc = (const float*)d_in[6];
    const float* bc = (const float*)d_in[7];
    float* out = (float*)d_out;

    const int n = in_sizes[0] / 128;   // 100000
    const int E = in_sizes[1] / 2;     // 600000

    const int* src = ei;
    const int* dst = ei + (size_t)E;

    const int nb = (n + SCAN_TILE - 1) / SCAN_TILE;   // 49 blocks (<=256)

    // ws layout (4B elems): dinv[n] | deg/cursor[n] | row_ptr[n+1] | col[E]
    //                       | bsum[256] | bufA[64n] | bufB[64n]
    float* dinv    = (float*)d_ws;
    int*   deg     = (int*)d_ws + n;
    int*   row_ptr = (int*)d_ws + 2 * (size_t)n;
    int*   col     = row_ptr + (n + 1);
    int*   bsum    = col + E;
    float* bufA    = (float*)(bsum + 256);     // h1', then h2'
    float* bufB    = bufA + (size_t)n * 64;    // hr1

    hipMemsetAsync(deg, 0, (size_t)n * 4, stream);
    count_kernel<<<(E + 255) / 256, 256, 0, stream>>>(dst, deg, E);
    tile_reduce_kernel<<<nb, SCAN_THREADS, 0, stream>>>(deg, bsum, n);
    scan_bsums_kernel<<<1, SCAN_THREADS, 0, stream>>>(bsum, row_ptr, nb, n);
    tile_apply_kernel<<<nb, SCAN_THREADS, 0, stream>>>(deg, bsum, row_ptr, dinv, n);
    fill_kernel<<<(E + 255) / 256, 256, 0, stream>>>(src, dst, deg, col, E);

    const int gemm_grid = (n + 127) / 128;   // BM=128 nodes per block

    // Layer 1: TM=8, TN=4
    gemm_tiled<128, 64, 128, 8, 4><<<gemm_grid, 256, 0, stream>>>(x, W1, dinv, bufA, n);
    agg_relu_kernel<64><<<(n * 16 + 255) / 256, 256, 0, stream>>>(row_ptr, col, dinv,
                                                                  bufA, b1, bufB, n);
    // Layer 2 + head: TM=4, TN=4
    gemm_tiled<64, 32, 128, 4, 4><<<gemm_grid, 256, 0, stream>>>(bufB, W2, dinv, bufA, n);
    agg_final_kernel<<<(n * 8 + 255) / 256, 256, 0, stream>>>(row_ptr, col, dinv,
                                                              bufA, b2, Wc, bc, out, n);
}